// Round 1
// 269.007 us; speedup vs baseline: 1.0117x; 1.0117x over previous
//
#include <hip/hip_runtime.h>
#include <hip/hip_bf16.h>

// LightGCN layer: out[v] = sum_{(u->v)} w * x[u], N=100K, E=1.6M, D=128, fp32.
//
// R9: R8 measured gather at Occupancy=30%, VALUBusy=15.6%, 3.44 TB/s eff.
// Diagnosis: latency-bound, not BW-bound — grid 782 x 4 waves = ~12 waves/CU
// can't keep enough random 512B x-row reads in flight; front-end (hist +
// scatter) ran on 128 blocks x 256 thr = 12.5% of the machine's wave slots.
// Fix: concurrency on both axes.
//   - gather: 512 threads (8 waves), nodes strided by 8 -> ~24 waves/CU.
//   - hist/scatter: SBLK 128->256 blocks AND 512 threads (4x waves).
//     Per-(block,bucket) CSR run ~8 edges = one 64B line -> write-amp ~1.
//   - scan: generalized to SBLK=256 (i>>8), tstate 128 slots, ntiles<=128.
// Dispatches: hist -> scan -> scatter -> gather (4). No global atomics.

constexpr int D_FEAT = 128;
constexpr int NPB = 128;        // nodes per bucket (dst >> 7)
constexpr int SBLK = 256;       // hist/scatter block count
constexpr int LOG_SBLK = 8;
constexpr int STILE = 2048;     // scan tile (256 thr x 8)
constexpr int CAP = 3072;       // max edges per bucket staged in LDS

typedef float v4f __attribute__((ext_vector_type(4)));

// ---------------- fallback (R1) ----------------
__global__ __launch_bounds__(256) void scatter_atomic_kernel(
    const float* __restrict__ x, const float* __restrict__ w,
    const int* __restrict__ src_idx, const int* __restrict__ dst_idx,
    float* __restrict__ out, int n_edges) {
  long long tid = (long long)blockIdx.x * blockDim.x + threadIdx.x;
  int lane = (int)(tid & 31);
  long long e = tid >> 5;
  if (e >= n_edges) return;
  int s = src_idx[e];
  int d = dst_idx[e];
  float wt = w[e];
  float4 v = ((const float4*)(x + (size_t)s * D_FEAT))[lane];
  float* o = out + (size_t)d * D_FEAT + (size_t)lane * 4;
  atomicAdd(o + 0, v.x * wt);
  atomicAdd(o + 1, v.y * wt);
  atomicAdd(o + 2, v.z * wt);
  atomicAdd(o + 3, v.w * wt);
}

// block-wide exclusive scan over blockDim.x threads (any multiple of 64,
// up to 512); sh holds >= (nwaves+1) ints (declare 9).
__device__ __forceinline__ int block_excl_scan(int v, int* sh, int* total) {
  const int lane = threadIdx.x & 63;
  const int wid = threadIdx.x >> 6;
  const int nw = blockDim.x >> 6;
  int inc = v;
  #pragma unroll
  for (int o = 1; o < 64; o <<= 1) {
    int t = __shfl_up(inc, o, 64);
    if (lane >= o) inc += t;
  }
  if (lane == 63) sh[wid] = inc;
  __syncthreads();
  if (threadIdx.x == 0) {
    int a = 0;
    for (int k = 0; k < nw; ++k) { int t = sh[k]; sh[k] = a; a += t; }
    sh[nw] = a;
  }
  __syncthreads();
  int r = sh[wid] + inc - v;
  if (total) *total = sh[nw];
  __syncthreads();
  return r;
}

// ---------------- phase 1: per-block bucket hist (private slices) ----------
__global__ __launch_bounds__(512) void hist_kernel(
    const int* __restrict__ dst, int* __restrict__ hist, int n_edges,
    int nbk, int tile) {
  __shared__ int h[1024];
  const int tid = threadIdx.x;
  const int b = blockIdx.x;
  for (int i = tid; i < nbk; i += 512) h[i] = 0;
  __syncthreads();
  int base = b * tile;
  int lim = min(base + tile, n_edges);
  for (int i = base + tid; i < lim; i += 512)
    atomicAdd(&h[((unsigned)dst[i]) >> 7], 1);
  __syncthreads();
  for (int k = tid; k < nbk; k += 512) hist[b * nbk + k] = h[k];  // full overwrite
}

// ---------------- phase 2: lookback scan over transposed hist ----------
// flat i = bucket*SBLK + block; value = hist[block*nbk + bucket].
// tstate poison (0xAAAA... high word) = invalid; 1 = aggregate, 2 = prefix.
__global__ __launch_bounds__(256) void scan_kernel(
    const int* __restrict__ hist, int* __restrict__ off_flat,
    unsigned long long* __restrict__ tstate, int nbk, int n_edges) {
  __shared__ int sh[9];
  __shared__ int s_prefix;
  const int tid = threadIdx.x;
  const int blk = blockIdx.x;
  const int n_scan = nbk * SBLK;
  const int base = blk * STILE + tid * 8;

  int c[8];
  #pragma unroll
  for (int k = 0; k < 8; ++k) {
    int i = base + k;
    c[k] = (i < n_scan) ? hist[(i & (SBLK - 1)) * nbk + (i >> LOG_SBLK)] : 0;
  }
  int p[8];
  int tsum = 0;
  #pragma unroll
  for (int k = 0; k < 8; ++k) { p[k] = tsum; tsum += c[k]; }

  int total;
  int tex = block_excl_scan(tsum, sh, &total);

  if (tid == 0) {
    int excl = 0;
    if (blk == 0) {
      __hip_atomic_store(&tstate[0], (2ULL << 32) | (unsigned)total,
                         __ATOMIC_RELEASE, __HIP_MEMORY_SCOPE_AGENT);
    } else {
      __hip_atomic_store(&tstate[blk], (1ULL << 32) | (unsigned)total,
                         __ATOMIC_RELEASE, __HIP_MEMORY_SCOPE_AGENT);
      int pidx = blk - 1;
      int run = 0;
      while (true) {
        unsigned long long v = __hip_atomic_load(
            &tstate[pidx], __ATOMIC_ACQUIRE, __HIP_MEMORY_SCOPE_AGENT);
        unsigned st = (unsigned)(v >> 32);
        if (st != 1u && st != 2u) { __builtin_amdgcn_s_sleep(1); continue; }
        run += (int)(unsigned)v;
        if (st == 2u) break;
        --pidx;
      }
      excl = run;
      __hip_atomic_store(&tstate[blk],
                         (2ULL << 32) | (unsigned)(excl + total),
                         __ATOMIC_RELEASE, __HIP_MEMORY_SCOPE_AGENT);
    }
    s_prefix = excl;
  }
  __syncthreads();

  int my = s_prefix + tex;
  if (base + 8 <= n_scan) {
    ((int4*)(off_flat + base))[0] =
        make_int4(my + p[0], my + p[1], my + p[2], my + p[3]);
    ((int4*)(off_flat + base))[1] =
        make_int4(my + p[4], my + p[5], my + p[6], my + p[7]);
  } else {
    #pragma unroll
    for (int k = 0; k < 8; ++k)
      if (base + k < n_scan) off_flat[base + k] = my + p[k];
  }
  if (blk == 0 && tid == 0) off_flat[n_scan] = n_edges;
}

// ---------------- phase 3: deterministic scatter (no global atomics) -------
__global__ __launch_bounds__(512) void scatter_kernel(
    const int* __restrict__ src, const int* __restrict__ dst,
    const float* __restrict__ w, const int* __restrict__ off_flat,
    uint2* __restrict__ csr, int n_edges, int nbk, int tile) {
  __shared__ int cur[1024];
  const int tid = threadIdx.x;
  const int b = blockIdx.x;
  for (int k = tid; k < nbk; k += 512) cur[k] = off_flat[k * SBLK + b];
  __syncthreads();
  int base = b * tile;
  int lim = min(base + tile, n_edges);
  for (int i = base + tid; i < lim; i += 512) {
    unsigned d = (unsigned)dst[i];
    unsigned k = d >> 7;
    unsigned dl = d & 127u;
    int pos = atomicAdd(&cur[k], 1);          // LDS atomic
    csr[pos] = make_uint2((unsigned)src[i] | (dl << 20), __float_as_uint(w[i]));
  }
}

// ---------------- phase 4: gather (LDS perm-sort + register accumulate) ----
__global__ __launch_bounds__(512) void gather_kernel(
    const float* __restrict__ x, const int* __restrict__ off_flat,
    const uint2* __restrict__ csr, float* __restrict__ out, int n_nodes) {
  __shared__ uint2 eds[CAP];        // 24 KB staged edges
  __shared__ unsigned short perm[CAP];  // 6 KB sorted order
  __shared__ int loff[NPB + 1];
  __shared__ int lcur[NPB];
  __shared__ int sh[9];

  const int b = blockIdx.x;
  const int tid = threadIdx.x;
  const int beg = off_flat[b * SBLK];
  const int end = off_flat[(b + 1) * SBLK];
  const int cnt = end - beg;
  const int nbase = b * NPB;

  const int wv = tid >> 6;
  const int lane = tid & 63;
  const int f = lane & 31;
  const int half = lane >> 5;
  const float4* X = (const float4*)x;

  if (cnt <= CAP) {
    // stage + local hist
    if (tid < NPB) lcur[tid] = 0;
    __syncthreads();
    for (int i = tid; i < cnt; i += 512) {
      uint2 e = csr[beg + i];
      eds[i] = e;
      atomicAdd(&lcur[e.x >> 20], 1);
    }
    __syncthreads();
    // scan 128 counters -> loff, reset lcur as cursor
    {
      int v = (tid < NPB) ? lcur[tid] : 0;
      int ex = block_excl_scan(v, sh, nullptr);
      __syncthreads();
      if (tid < NPB) { loff[tid] = ex; lcur[tid] = 0; }
      if (tid == 0) loff[NPB] = cnt;
    }
    __syncthreads();
    // build perm (counting-sort placement)
    for (int i = tid; i < cnt; i += 512) {
      int dl = eds[i].x >> 20;
      int pos = loff[dl] + atomicAdd(&lcur[dl], 1);
      perm[pos] = (unsigned short)i;
    }
    __syncthreads();

    // register-accumulate per node (1 wave/node, 2 halves x unroll4)
    for (int n = wv; n < NPB; n += 8) {
      int node = nbase + n;
      if (node >= n_nodes) break;
      int jb = loff[n];
      int je = loff[n + 1];
      float4 a0 = make_float4(0.f, 0.f, 0.f, 0.f);
      float4 a1 = make_float4(0.f, 0.f, 0.f, 0.f);
      float4 a2 = make_float4(0.f, 0.f, 0.f, 0.f);
      float4 a3 = make_float4(0.f, 0.f, 0.f, 0.f);
      int j = jb + half;
      for (; j + 6 < je; j += 8) {
        uint2 e0 = eds[perm[j]];
        uint2 e1 = eds[perm[j + 2]];
        uint2 e2 = eds[perm[j + 4]];
        uint2 e3 = eds[perm[j + 6]];
        float4 v0 = X[(size_t)(e0.x & 0xFFFFFu) * 32 + f];
        float4 v1 = X[(size_t)(e1.x & 0xFFFFFu) * 32 + f];
        float4 v2 = X[(size_t)(e2.x & 0xFFFFFu) * 32 + f];
        float4 v3 = X[(size_t)(e3.x & 0xFFFFFu) * 32 + f];
        float w0 = __uint_as_float(e0.y);
        float w1 = __uint_as_float(e1.y);
        float w2 = __uint_as_float(e2.y);
        float w3 = __uint_as_float(e3.y);
        a0.x += w0 * v0.x; a0.y += w0 * v0.y; a0.z += w0 * v0.z; a0.w += w0 * v0.w;
        a1.x += w1 * v1.x; a1.y += w1 * v1.y; a1.z += w1 * v1.z; a1.w += w1 * v1.w;
        a2.x += w2 * v2.x; a2.y += w2 * v2.y; a2.z += w2 * v2.z; a2.w += w2 * v2.w;
        a3.x += w3 * v3.x; a3.y += w3 * v3.y; a3.z += w3 * v3.z; a3.w += w3 * v3.w;
      }
      for (; j < je; j += 2) {
        uint2 e0 = eds[perm[j]];
        float4 v0 = X[(size_t)(e0.x & 0xFFFFFu) * 32 + f];
        float w0 = __uint_as_float(e0.y);
        a0.x += w0 * v0.x; a0.y += w0 * v0.y; a0.z += w0 * v0.z; a0.w += w0 * v0.w;
      }
      a0.x += a1.x + a2.x + a3.x;
      a0.y += a1.y + a2.y + a3.y;
      a0.z += a1.z + a2.z + a3.z;
      a0.w += a1.w + a2.w + a3.w;
      a0.x += __shfl_xor(a0.x, 32, 64);
      a0.y += __shfl_xor(a0.y, 32, 64);
      a0.z += __shfl_xor(a0.z, 32, 64);
      a0.w += __shfl_xor(a0.w, 32, 64);
      if (half == 0) {
        v4f val = {a0.x, a0.y, a0.z, a0.w};
        __builtin_nontemporal_store(val, (v4f*)out + (size_t)node * 32 + f);
      }
    }
  } else {
    // safety net (statistically unreachable): per-node scan of the bucket
    for (int n = wv; n < NPB; n += 8) {
      int node = nbase + n;
      if (node >= n_nodes) break;
      float4 a0 = make_float4(0.f, 0.f, 0.f, 0.f);
      for (int j = half; j < cnt; j += 2) {
        uint2 e = csr[beg + j];
        if ((int)(e.x >> 20) == n) {
          float4 v = X[(size_t)(e.x & 0xFFFFFu) * 32 + f];
          float wt = __uint_as_float(e.y);
          a0.x += wt * v.x; a0.y += wt * v.y; a0.z += wt * v.z; a0.w += wt * v.w;
        }
      }
      a0.x += __shfl_xor(a0.x, 32, 64);
      a0.y += __shfl_xor(a0.y, 32, 64);
      a0.z += __shfl_xor(a0.z, 32, 64);
      a0.w += __shfl_xor(a0.w, 32, 64);
      if (half == 0) {
        v4f val = {a0.x, a0.y, a0.z, a0.w};
        __builtin_nontemporal_store(val, (v4f*)out + (size_t)node * 32 + f);
      }
    }
  }
}

extern "C" void kernel_launch(void* const* d_in, const int* in_sizes, int n_in,
                              void* d_out, int out_size, void* d_ws, size_t ws_size,
                              hipStream_t stream) {
  const float* x  = (const float*)d_in[0];
  const float* w  = (const float*)d_in[1];
  const int* eidx = (const int*)d_in[2];

  int n_edges = in_sizes[1];           // E
  int n_nodes = out_size / D_FEAT;     // N
  const int* src = eidx;
  const int* dst = eidx + n_edges;
  float* out = (float*)d_out;

  const int nbk = (n_nodes + NPB - 1) / NPB;       // buckets (782 @100K)
  const int tile = (n_edges + SBLK - 1) / SBLK;    // edges per hist/scatter blk
  const int n_scan = nbk * SBLK;
  const int ntiles = (n_scan + STILE - 1) / STILE; // scan blocks (<=128)

  // ws layout (16B-aligned segments):
  //   hist:     SBLK*nbk ints
  //   off_flat: n_scan+4 ints (n_scan+1 used)
  //   tstate:   128 u64 (poison = invalid state; no memset needed)
  //   csr:      E uint2
  const size_t n_hist = (size_t)SBLK * nbk;
  const size_t n_off = (size_t)n_scan + 4;
  size_t need = (n_hist + n_off) * 4 + 128 * 8 + (size_t)n_edges * 8;
  if (ws_size < need || nbk > 1024 || ntiles > 128 || n_nodes >= (1 << 20)) {
    hipMemsetAsync(d_out, 0, (size_t)out_size * sizeof(float), stream);
    long long total_threads = (long long)n_edges * 32;
    long long grid = (total_threads + 255) / 256;
    scatter_atomic_kernel<<<(dim3)(unsigned)grid, 256, 0, stream>>>(
        x, w, src, dst, out, n_edges);
    return;
  }

  int* hist = (int*)d_ws;                                  // SBLK*nbk
  int* off_flat = hist + n_hist;                           // n_scan+4
  unsigned long long* tstate = (unsigned long long*)(off_flat + n_off);
  uint2* csr = (uint2*)(tstate + 128);                     // E

  hist_kernel<<<SBLK, 512, 0, stream>>>(dst, hist, n_edges, nbk, tile);
  scan_kernel<<<ntiles, 256, 0, stream>>>(hist, off_flat, tstate, nbk,
                                          n_edges);
  scatter_kernel<<<SBLK, 512, 0, stream>>>(src, dst, w, off_flat, csr,
                                           n_edges, nbk, tile);
  gather_kernel<<<nbk, 512, 0, stream>>>(x, off_flat, csr, out, n_nodes);
}

// Round 2
// 267.408 us; speedup vs baseline: 1.0178x; 1.0060x over previous
//
#include <hip/hip_runtime.h>
#include <hip/hip_bf16.h>

// LightGCN layer: out[v] = sum_{(u->v)} w * x[u], N=100K, E=1.6M, D=128, fp32.
//
// R10: R9 post-mortem — gather occupancy 30->52% but BW DROPPED (3.44->3.2
// TB/s, VGPR 44->32): 512-thr blocks destroyed per-wave ILP; waves are not
// the lever, in-flight row loads are. Front-end barely moved (146->133us)
// despite 4x waves => not BW-bound; suspect scan's serial lookback (tid==0
// walks up to 97 predecessors at ~0.5us/agent-load).
// Fixes:
//   - gather: 256 thr again; feature-split (2 blocks/bucket, 64 feats each);
//     4 lane-quarters x unroll4 => 16 rows in flight per wave (vs 8).
//   - scan: wave-parallel lookback (64 lanes poll 64 predecessors, ballot +
//     ffsll + shuffle-reduce) => <=2 window rounds instead of ~97 serial.
// Dispatches: hist -> scan -> scatter -> gather (4). No global atomics.

constexpr int D_FEAT = 128;
constexpr int NPB = 128;        // nodes per bucket (dst >> 7)
constexpr int SBLK = 256;       // hist/scatter block count
constexpr int LOG_SBLK = 8;
constexpr int STILE = 2048;     // scan tile (256 thr x 8)
constexpr int CAP = 3072;       // max edges per bucket staged in LDS

typedef float v4f __attribute__((ext_vector_type(4)));

// ---------------- fallback (R1) ----------------
__global__ __launch_bounds__(256) void scatter_atomic_kernel(
    const float* __restrict__ x, const float* __restrict__ w,
    const int* __restrict__ src_idx, const int* __restrict__ dst_idx,
    float* __restrict__ out, int n_edges) {
  long long tid = (long long)blockIdx.x * blockDim.x + threadIdx.x;
  int lane = (int)(tid & 31);
  long long e = tid >> 5;
  if (e >= n_edges) return;
  int s = src_idx[e];
  int d = dst_idx[e];
  float wt = w[e];
  float4 v = ((const float4*)(x + (size_t)s * D_FEAT))[lane];
  float* o = out + (size_t)d * D_FEAT + (size_t)lane * 4;
  atomicAdd(o + 0, v.x * wt);
  atomicAdd(o + 1, v.y * wt);
  atomicAdd(o + 2, v.z * wt);
  atomicAdd(o + 3, v.w * wt);
}

// block-wide exclusive scan over blockDim.x threads (any multiple of 64,
// up to 512); sh holds >= (nwaves+1) ints (declare 9).
__device__ __forceinline__ int block_excl_scan(int v, int* sh, int* total) {
  const int lane = threadIdx.x & 63;
  const int wid = threadIdx.x >> 6;
  const int nw = blockDim.x >> 6;
  int inc = v;
  #pragma unroll
  for (int o = 1; o < 64; o <<= 1) {
    int t = __shfl_up(inc, o, 64);
    if (lane >= o) inc += t;
  }
  if (lane == 63) sh[wid] = inc;
  __syncthreads();
  if (threadIdx.x == 0) {
    int a = 0;
    for (int k = 0; k < nw; ++k) { int t = sh[k]; sh[k] = a; a += t; }
    sh[nw] = a;
  }
  __syncthreads();
  int r = sh[wid] + inc - v;
  if (total) *total = sh[nw];
  __syncthreads();
  return r;
}

// ---------------- phase 1: per-block bucket hist (private slices) ----------
__global__ __launch_bounds__(512) void hist_kernel(
    const int* __restrict__ dst, int* __restrict__ hist, int n_edges,
    int nbk, int tile) {
  __shared__ int h[1024];
  const int tid = threadIdx.x;
  const int b = blockIdx.x;
  for (int i = tid; i < nbk; i += 512) h[i] = 0;
  __syncthreads();
  int base = b * tile;
  int lim = min(base + tile, n_edges);
  for (int i = base + tid; i < lim; i += 512)
    atomicAdd(&h[((unsigned)dst[i]) >> 7], 1);
  __syncthreads();
  for (int k = tid; k < nbk; k += 512) hist[b * nbk + k] = h[k];  // full overwrite
}

// ---------------- phase 2: lookback scan over transposed hist ----------
// flat i = bucket*SBLK + block; value = hist[block*nbk + bucket].
// tstate poison (0xAAAA... high word) = invalid; 1 = aggregate, 2 = prefix.
// Lookback is WAVE-PARALLEL: 64 lanes poll 64 predecessors at once.
__global__ __launch_bounds__(256) void scan_kernel(
    const int* __restrict__ hist, int* __restrict__ off_flat,
    unsigned long long* __restrict__ tstate, int nbk, int n_edges) {
  __shared__ int sh[9];
  __shared__ int s_prefix;
  const int tid = threadIdx.x;
  const int blk = blockIdx.x;
  const int n_scan = nbk * SBLK;
  const int base = blk * STILE + tid * 8;

  int c[8];
  #pragma unroll
  for (int k = 0; k < 8; ++k) {
    int i = base + k;
    c[k] = (i < n_scan) ? hist[(i & (SBLK - 1)) * nbk + (i >> LOG_SBLK)] : 0;
  }
  int p[8];
  int tsum = 0;
  #pragma unroll
  for (int k = 0; k < 8; ++k) { p[k] = tsum; tsum += c[k]; }

  int total;
  int tex = block_excl_scan(tsum, sh, &total);

  if (blk == 0) {
    if (tid == 0) {
      __hip_atomic_store(&tstate[0], (2ULL << 32) | (unsigned)total,
                         __ATOMIC_RELEASE, __HIP_MEMORY_SCOPE_AGENT);
      s_prefix = 0;
    }
  } else {
    if (tid == 0)
      __hip_atomic_store(&tstate[blk], (1ULL << 32) | (unsigned)total,
                         __ATOMIC_RELEASE, __HIP_MEMORY_SCOPE_AGENT);
    if (tid < 64) {
      int pidx = blk - 1 - tid;
      int run = 0;
      while (true) {
        unsigned long long v;
        unsigned st;
        if (pidx >= 0) {
          do {
            v = __hip_atomic_load(&tstate[pidx], __ATOMIC_ACQUIRE,
                                  __HIP_MEMORY_SCOPE_AGENT);
            st = (unsigned)(v >> 32);
            if (st != 1u && st != 2u) __builtin_amdgcn_s_sleep(1);
          } while (st != 1u && st != 2u);
        } else {
          v = (2ULL << 32);  // block "-1": prefix 0
          st = 2u;
        }
        unsigned long long pmask = __ballot(st == 2u);
        int lfirst = (int)__ffsll((long long)pmask) - 1;  // closest prefix
        int contrib = (lfirst < 0 || tid <= lfirst) ? (int)(unsigned)v : 0;
        #pragma unroll
        for (int o = 32; o; o >>= 1) contrib += __shfl_xor(contrib, o, 64);
        run += contrib;
        if (lfirst >= 0) break;
        pidx -= 64;
      }
      if (tid == 0) {
        __hip_atomic_store(&tstate[blk],
                           (2ULL << 32) | (unsigned)(run + total),
                           __ATOMIC_RELEASE, __HIP_MEMORY_SCOPE_AGENT);
        s_prefix = run;
      }
    }
  }
  __syncthreads();

  int my = s_prefix + tex;
  if (base + 8 <= n_scan) {
    ((int4*)(off_flat + base))[0] =
        make_int4(my + p[0], my + p[1], my + p[2], my + p[3]);
    ((int4*)(off_flat + base))[1] =
        make_int4(my + p[4], my + p[5], my + p[6], my + p[7]);
  } else {
    #pragma unroll
    for (int k = 0; k < 8; ++k)
      if (base + k < n_scan) off_flat[base + k] = my + p[k];
  }
  if (blk == 0 && tid == 0) off_flat[n_scan] = n_edges;
}

// ---------------- phase 3: deterministic scatter (no global atomics) -------
__global__ __launch_bounds__(512) void scatter_kernel(
    const int* __restrict__ src, const int* __restrict__ dst,
    const float* __restrict__ w, const int* __restrict__ off_flat,
    uint2* __restrict__ csr, int n_edges, int nbk, int tile) {
  __shared__ int cur[1024];
  const int tid = threadIdx.x;
  const int b = blockIdx.x;
  for (int k = tid; k < nbk; k += 512) cur[k] = off_flat[k * SBLK + b];
  __syncthreads();
  int base = b * tile;
  int lim = min(base + tile, n_edges);
  for (int i = base + tid; i < lim; i += 512) {
    unsigned d = (unsigned)dst[i];
    unsigned k = d >> 7;
    unsigned dl = d & 127u;
    int pos = atomicAdd(&cur[k], 1);          // LDS atomic
    csr[pos] = make_uint2((unsigned)src[i] | (dl << 20), __float_as_uint(w[i]));
  }
}

// ---------------- phase 4: gather (LDS perm-sort + register accumulate) ----
// Feature-split: 2 blocks per bucket; block handles 64 of 128 features.
// Wave = 4 lane-quarters (16 lanes) x unroll4 => 16 rows in flight.
__global__ __launch_bounds__(256) void gather_kernel(
    const float* __restrict__ x, const int* __restrict__ off_flat,
    const uint2* __restrict__ csr, float* __restrict__ out, int n_nodes) {
  __shared__ uint2 eds[CAP];        // 24 KB staged edges
  __shared__ unsigned short perm[CAP];  // 6 KB sorted order
  __shared__ int loff[NPB + 1];
  __shared__ int lcur[NPB];
  __shared__ int sh[9];

  const int b = blockIdx.x >> 1;
  const int fh = blockIdx.x & 1;    // feature half (0: f4 0..15, 1: f4 16..31)
  const int tid = threadIdx.x;
  const int beg = off_flat[b * SBLK];
  const int end = off_flat[(b + 1) * SBLK];
  const int cnt = end - beg;
  const int nbase = b * NPB;

  const int wv = tid >> 6;
  const int lane = tid & 63;
  const int q = lane >> 4;               // quarter 0..3 (edge slot)
  const int f = (lane & 15) + fh * 16;   // float4 index within row
  const float4* X = (const float4*)x;

  if (cnt <= CAP) {
    // stage + local hist
    if (tid < NPB) lcur[tid] = 0;
    __syncthreads();
    for (int i = tid; i < cnt; i += 256) {
      uint2 e = csr[beg + i];
      eds[i] = e;
      atomicAdd(&lcur[e.x >> 20], 1);
    }
    __syncthreads();
    // scan 128 counters -> loff, reset lcur as cursor
    {
      int v = (tid < NPB) ? lcur[tid] : 0;
      int ex = block_excl_scan(v, sh, nullptr);
      __syncthreads();
      if (tid < NPB) { loff[tid] = ex; lcur[tid] = 0; }
      if (tid == 0) loff[NPB] = cnt;
    }
    __syncthreads();
    // build perm (counting-sort placement)
    for (int i = tid; i < cnt; i += 256) {
      int dl = eds[i].x >> 20;
      int pos = loff[dl] + atomicAdd(&lcur[dl], 1);
      perm[pos] = (unsigned short)i;
    }
    __syncthreads();

    // register-accumulate per node (1 wave/node, 4 quarters x unroll4)
    for (int n = wv; n < NPB; n += 4) {
      int node = nbase + n;
      if (node >= n_nodes) break;
      int jb = loff[n];
      int je = loff[n + 1];
      float4 a0 = make_float4(0.f, 0.f, 0.f, 0.f);
      float4 a1 = make_float4(0.f, 0.f, 0.f, 0.f);
      float4 a2 = make_float4(0.f, 0.f, 0.f, 0.f);
      float4 a3 = make_float4(0.f, 0.f, 0.f, 0.f);
      int j = jb + q;
      for (; j + 12 < je; j += 16) {
        uint2 e0 = eds[perm[j]];
        uint2 e1 = eds[perm[j + 4]];
        uint2 e2 = eds[perm[j + 8]];
        uint2 e3 = eds[perm[j + 12]];
        float4 v0 = X[(size_t)(e0.x & 0xFFFFFu) * 32 + f];
        float4 v1 = X[(size_t)(e1.x & 0xFFFFFu) * 32 + f];
        float4 v2 = X[(size_t)(e2.x & 0xFFFFFu) * 32 + f];
        float4 v3 = X[(size_t)(e3.x & 0xFFFFFu) * 32 + f];
        float w0 = __uint_as_float(e0.y);
        float w1 = __uint_as_float(e1.y);
        float w2 = __uint_as_float(e2.y);
        float w3 = __uint_as_float(e3.y);
        a0.x += w0 * v0.x; a0.y += w0 * v0.y; a0.z += w0 * v0.z; a0.w += w0 * v0.w;
        a1.x += w1 * v1.x; a1.y += w1 * v1.y; a1.z += w1 * v1.z; a1.w += w1 * v1.w;
        a2.x += w2 * v2.x; a2.y += w2 * v2.y; a2.z += w2 * v2.z; a2.w += w2 * v2.w;
        a3.x += w3 * v3.x; a3.y += w3 * v3.y; a3.z += w3 * v3.z; a3.w += w3 * v3.w;
      }
      for (; j < je; j += 4) {
        uint2 e0 = eds[perm[j]];
        float4 v0 = X[(size_t)(e0.x & 0xFFFFFu) * 32 + f];
        float w0 = __uint_as_float(e0.y);
        a0.x += w0 * v0.x; a0.y += w0 * v0.y; a0.z += w0 * v0.z; a0.w += w0 * v0.w;
      }
      a0.x += a1.x + a2.x + a3.x;
      a0.y += a1.y + a2.y + a3.y;
      a0.z += a1.z + a2.z + a3.z;
      a0.w += a1.w + a2.w + a3.w;
      // reduce across the 4 quarters
      a0.x += __shfl_xor(a0.x, 16, 64);
      a0.y += __shfl_xor(a0.y, 16, 64);
      a0.z += __shfl_xor(a0.z, 16, 64);
      a0.w += __shfl_xor(a0.w, 16, 64);
      a0.x += __shfl_xor(a0.x, 32, 64);
      a0.y += __shfl_xor(a0.y, 32, 64);
      a0.z += __shfl_xor(a0.z, 32, 64);
      a0.w += __shfl_xor(a0.w, 32, 64);
      if (q == 0) {
        v4f val = {a0.x, a0.y, a0.z, a0.w};
        __builtin_nontemporal_store(val, (v4f*)out + (size_t)node * 32 + f);
      }
    }
  } else {
    // safety net (statistically unreachable): per-node scan of the bucket
    for (int n = wv; n < NPB; n += 4) {
      int node = nbase + n;
      if (node >= n_nodes) break;
      float4 a0 = make_float4(0.f, 0.f, 0.f, 0.f);
      for (int j = q; j < cnt; j += 4) {
        uint2 e = csr[beg + j];
        if ((int)(e.x >> 20) == n) {
          float4 v = X[(size_t)(e.x & 0xFFFFFu) * 32 + f];
          float wt = __uint_as_float(e.y);
          a0.x += wt * v.x; a0.y += wt * v.y; a0.z += wt * v.z; a0.w += wt * v.w;
        }
      }
      a0.x += __shfl_xor(a0.x, 16, 64);
      a0.y += __shfl_xor(a0.y, 16, 64);
      a0.z += __shfl_xor(a0.z, 16, 64);
      a0.w += __shfl_xor(a0.w, 16, 64);
      a0.x += __shfl_xor(a0.x, 32, 64);
      a0.y += __shfl_xor(a0.y, 32, 64);
      a0.z += __shfl_xor(a0.z, 32, 64);
      a0.w += __shfl_xor(a0.w, 32, 64);
      if (q == 0) {
        v4f val = {a0.x, a0.y, a0.z, a0.w};
        __builtin_nontemporal_store(val, (v4f*)out + (size_t)node * 32 + f);
      }
    }
  }
}

extern "C" void kernel_launch(void* const* d_in, const int* in_sizes, int n_in,
                              void* d_out, int out_size, void* d_ws, size_t ws_size,
                              hipStream_t stream) {
  const float* x  = (const float*)d_in[0];
  const float* w  = (const float*)d_in[1];
  const int* eidx = (const int*)d_in[2];

  int n_edges = in_sizes[1];           // E
  int n_nodes = out_size / D_FEAT;     // N
  const int* src = eidx;
  const int* dst = eidx + n_edges;
  float* out = (float*)d_out;

  const int nbk = (n_nodes + NPB - 1) / NPB;       // buckets (782 @100K)
  const int tile = (n_edges + SBLK - 1) / SBLK;    // edges per hist/scatter blk
  const int n_scan = nbk * SBLK;
  const int ntiles = (n_scan + STILE - 1) / STILE; // scan blocks (<=128)

  // ws layout (16B-aligned segments):
  //   hist:     SBLK*nbk ints
  //   off_flat: n_scan+4 ints (n_scan+1 used)
  //   tstate:   128 u64 (poison = invalid state; no memset needed)
  //   csr:      E uint2
  const size_t n_hist = (size_t)SBLK * nbk;
  const size_t n_off = (size_t)n_scan + 4;
  size_t need = (n_hist + n_off) * 4 + 128 * 8 + (size_t)n_edges * 8;
  if (ws_size < need || nbk > 1024 || ntiles > 128 || n_nodes >= (1 << 20)) {
    hipMemsetAsync(d_out, 0, (size_t)out_size * sizeof(float), stream);
    long long total_threads = (long long)n_edges * 32;
    long long grid = (total_threads + 255) / 256;
    scatter_atomic_kernel<<<(dim3)(unsigned)grid, 256, 0, stream>>>(
        x, w, src, dst, out, n_edges);
    return;
  }

  int* hist = (int*)d_ws;                                  // SBLK*nbk
  int* off_flat = hist + n_hist;                           // n_scan+4
  unsigned long long* tstate = (unsigned long long*)(off_flat + n_off);
  uint2* csr = (uint2*)(tstate + 128);                     // E

  hist_kernel<<<SBLK, 512, 0, stream>>>(dst, hist, n_edges, nbk, tile);
  scan_kernel<<<ntiles, 256, 0, stream>>>(hist, off_flat, tstate, nbk,
                                          n_edges);
  scatter_kernel<<<SBLK, 512, 0, stream>>>(src, dst, w, off_flat, csr,
                                           n_edges, nbk, tile);
  gather_kernel<<<nbk * 2, 256, 0, stream>>>(x, off_flat, csr, out, n_nodes);
}